// Round 3
// baseline (8642.611 us; speedup 1.0000x reference)
//
#include <hip/hip_runtime.h>
#include <math.h>

#define B_   4096
#define S_   64
#define H_   128
#define N_   (B_*S_)

// ---- workspace float offsets ----
#define WS_WC    0        // [384][16]  combined obs->gi weights (padded f=16)
#define WS_BC    6144     // [384]      combined gi bias
#define WS_WAP   6528     // [128][16]  padded enc_air_w
#define WS_WQP   8576     // [128][128] wq * qln_w (folded)
#define WS_SQ    24960    // [128] row sums of wqp
#define WS_EQ    25088    // [128] wq@qln_b + bq
#define WS_KC    25216    // [128][4]  (wk*klnw)@enc_m_w
#define WS_EK1   25728    // [128] (wk*klnw)@enc_m_b
#define WS_SK    25856    // [128] rowsum(wk*klnw)
#define WS_EK2   25984    // [128] wk@kln_b + bk
#define WS_VC    26112    // [128][4]  wv@enc_m_w
#define WS_VB    26624    // [128] wv@enc_m_b + bv
#define WS_MV    26752    // [4] mean weights for keys_raw mean
#define WS_QQ    26756    // [16] 4x4 quadratic form for E[y^2]
#define WS_QLIN  26772    // [4]
#define WS_MBC   26776
#define WS_C0    26777
#define WS_AIR   27392    // [N_][128] air_feat / combined buffer (in-place)

__device__ __forceinline__ float dot4(float4 a, float4 b){
    return fmaf(a.x,b.x, fmaf(a.y,b.y, fmaf(a.z,b.z, a.w*b.w)));
}
__device__ __forceinline__ void acc4(float& acc, float4 a, float4 b){
    acc = fmaf(a.x,b.x,acc); acc = fmaf(a.y,b.y,acc);
    acc = fmaf(a.z,b.z,acc); acc = fmaf(a.w,b.w,acc);
}
__device__ __forceinline__ float sel4(const float v[4], int kc){
    float a = (kc&1) ? v[1] : v[0];
    float b = (kc&1) ? v[3] : v[2];
    return (kc&2) ? b : a;
}
// chunked LDS addressing: row pitch 168 floats, kc-chunk pitch 40 floats
// (32 used by h, floats 32..35 hold the obs slice for that chunk) -> conflict-free
__device__ __forceinline__ int caddr(int r, int c){
    return r*168 + (c>>5)*40 + (c&31);
}

// ---------------- precompute folded weights ----------------
__global__ void precompute_kernel(
    const float* __restrict__ enc_air_w, const float* __restrict__ enc_air_b,
    const float* __restrict__ enc_m_w,  const float* __restrict__ enc_m_b,
    const float* __restrict__ gru_wih,  const float* __restrict__ gru_bih,
    const float* __restrict__ qln_w, const float* __restrict__ qln_b,
    const float* __restrict__ kln_w, const float* __restrict__ kln_b,
    const float* __restrict__ attn_in_w, const float* __restrict__ attn_in_b,
    float* __restrict__ ws)
{
    int i = blockIdx.x*blockDim.x + threadIdx.x;
    if (i < 6144) {                       // Wc[o][f] = sum_k wih[o][k]*Wa[k][f]
        int o = i>>4, f = i&15; float a = 0.f;
        if (f < 15) for (int k=0;k<128;k++) a = fmaf(gru_wih[o*128+k], enc_air_w[k*15+f], a);
        ws[WS_WC+i] = a;
    } else if (i < 6528) {                // bc
        int o = i-6144; float a = gru_bih[o];
        for (int k=0;k<128;k++) a = fmaf(gru_wih[o*128+k], enc_air_b[k], a);
        ws[WS_BC+o] = a;
    } else if (i < 8576) {                // Wap padded
        int idx = i-6528; int j = idx>>4, f = idx&15;
        ws[WS_WAP+idx] = (f<15) ? enc_air_w[j*15+f] : 0.f;
    } else if (i < 24960) {               // wqp
        int idx = i-8576; int o = idx>>7, j = idx&127;
        ws[WS_WQP+idx] = attn_in_w[o*128+j]*qln_w[j];
    } else if (i < 25088) {               // sq
        int o = i-24960; float a=0.f;
        for (int j=0;j<128;j++) a = fmaf(attn_in_w[o*128+j], qln_w[j], a);
        ws[WS_SQ+o]=a;
    } else if (i < 25216) {               // eq
        int o = i-25088; float a = attn_in_b[o];
        for (int j=0;j<128;j++) a = fmaf(attn_in_w[o*128+j], qln_b[j], a);
        ws[WS_EQ+o]=a;
    } else if (i < 25728) {               // Kc
        int idx = i-25216; int o = idx>>2, f = idx&3; float a=0.f;
        for (int j=0;j<128;j++) a = fmaf(attn_in_w[(128+o)*128+j]*kln_w[j], enc_m_w[j*4+f], a);
        ws[WS_KC+idx]=a;
    } else if (i < 25856) {               // ek1
        int o = i-25728; float a=0.f;
        for (int j=0;j<128;j++) a = fmaf(attn_in_w[(128+o)*128+j]*kln_w[j], enc_m_b[j], a);
        ws[WS_EK1+o]=a;
    } else if (i < 25984) {               // sk
        int o = i-25856; float a=0.f;
        for (int j=0;j<128;j++) a = fmaf(attn_in_w[(128+o)*128+j], kln_w[j], a);
        ws[WS_SK+o]=a;
    } else if (i < 26112) {               // ek2
        int o = i-25984; float a = attn_in_b[128+o];
        for (int j=0;j<128;j++) a = fmaf(attn_in_w[(128+o)*128+j], kln_b[j], a);
        ws[WS_EK2+o]=a;
    } else if (i < 26624) {               // Vc
        int idx = i-26112; int o = idx>>2, f = idx&3; float a=0.f;
        for (int j=0;j<128;j++) a = fmaf(attn_in_w[(256+o)*128+j], enc_m_w[j*4+f], a);
        ws[WS_VC+idx]=a;
    } else if (i < 26752) {               // vb
        int o = i-26624; float a = attn_in_b[256+o];
        for (int j=0;j<128;j++) a = fmaf(attn_in_w[(256+o)*128+j], enc_m_b[j], a);
        ws[WS_VB+o]=a;
    } else if (i < 26756) {               // Mv
        int f = i-26752; float a=0.f;
        for (int j=0;j<128;j++) a += enc_m_w[j*4+f];
        ws[WS_MV+f]=a*(1.f/128.f);
    } else if (i < 26772) {               // QQ
        int idx = i-26756; int a4 = idx>>2, b4 = idx&3; float a=0.f;
        for (int j=0;j<128;j++) a = fmaf(enc_m_w[j*4+a4], enc_m_w[j*4+b4], a);
        ws[WS_QQ+idx]=a*(1.f/128.f);
    } else if (i < 26776) {               // qlin
        int f = i-26772; float a=0.f;
        for (int j=0;j<128;j++) a = fmaf(enc_m_b[j], enc_m_w[j*4+f], a);
        ws[WS_QLIN+f]=a*(2.f/128.f);
    } else if (i == 26776) {
        float a=0.f; for (int j=0;j<128;j++) a += enc_m_b[j];
        ws[WS_MBC]=a*(1.f/128.f);
    } else if (i == 26777) {
        float a=0.f; for (int j=0;j<128;j++) a = fmaf(enc_m_b[j], enc_m_b[j], a);
        ws[WS_C0]=a*(1.f/128.f);
    }
}

// ---------------- Kernel A: GRU, weight-stationary in VGPRs ----------------
// 256 blocks x 16 rows; thread (j=t>>2, kc=t&3) owns whh rows j chunk kc (32 floats/gate)
// + Wc r/z sub-chunk (folded into the dot via obs staged in LDS chunk slots).
// waves_per_eu(2): 8 waves/CU = 1 block/CU, VGPR budget 256 -> no spill.
__global__ __attribute__((amdgpu_waves_per_eu(2))) __launch_bounds__(512)
void gru_kernel(
    const float* __restrict__ obs, const float* __restrict__ h0,
    const float* __restrict__ whh, const float* __restrict__ bhh,
    const float* __restrict__ ba,  const float* __restrict__ ws,
    float* __restrict__ air, float* __restrict__ out)
{
    __shared__ float h_s[2][16*168];   // double-buffered h + obs slots
    __shared__ float air_s[16*168];

    const int t  = threadIdx.x;
    const int j  = t>>2, kc = t&3;
    const int row0 = blockIdx.x*16;

    // --- weights into registers (once): 26 float4 whh' + 4 Wc_n + 4 Wap = 136 f ---
    const float4* whh4 = (const float4*)whh;
    const float4* ws4  = (const float4*)ws;
    float4 wr4[9], wz4[9], wn4[8];
    #pragma unroll
    for (int i=0;i<8;i++){
        wr4[i] = whh4[(      j)*32 + kc*8 + i];
        wz4[i] = whh4[(128 + j)*32 + kc*8 + i];
        wn4[i] = whh4[(256 + j)*32 + kc*8 + i];
    }
    wr4[8] = ws4[(WS_WC>>2) + (      j)*4 + kc];
    wz4[8] = ws4[(WS_WC>>2) + (128 + j)*4 + kc];
    float4 wcn[4], wap[4];
    #pragma unroll
    for (int i=0;i<4;i++){
        wcn[i] = ws4[(WS_WC>>2)  + (256 + j)*4 + i];
        wap[i] = ws4[(WS_WAP>>2) + j*4 + i];
    }
    const float bcrt = ws[WS_BC+j]     + bhh[j];
    const float bczt = ws[WS_BC+128+j] + bhh[128+j];
    const float bcn  = ws[WS_BC+256+j];
    const float bhn  = bhh[256+j];
    const float baj  = ba[j];
    const int jaddr_off = (j>>5)*40 + (j&31);

    // --- stage h0 into buf0 + obs(0) into buf0 slots ---
    {
        int rr = t>>5, c0 = (t&31)*4;
        float4 hv = *(const float4*)&h0[(size_t)(row0+rr)*128 + c0];
        *(float4*)&h_s[0][caddr(rr,c0)] = hv;
    }
    if (t < 256) {
        int rr = t>>4, c = t&15;
        h_s[0][rr*168 + (c>>2)*40 + 32 + (c&3)] =
            (c<15) ? obs[((size_t)(row0+rr)*64 + 0)*15 + c] : 0.f;
    }
    __syncthreads();

    for (int s=0;s<64;s++){
        const float* hcur = h_s[s&1];
        float*       hnxt = h_s[(s+1)&1];

        #pragma unroll
        for (int q=0;q<4;q++){
            float pr[4],pz[4],pn[4];
            #pragma unroll
            for (int rq=0;rq<4;rq++){ pr[rq]=0.f; pz[rq]=0.f; pn[rq]=0.f; }
            #pragma unroll
            for (int rq=0;rq<4;rq++){
                const float* hb = &hcur[(q*4+rq)*168 + kc*40];
                #pragma unroll
                for (int i=0;i<8;i++){
                    float4 hv = *(const float4*)&hb[i*4];
                    acc4(pr[rq],hv,wr4[i]);
                    acc4(pz[rq],hv,wz4[i]);
                    acc4(pn[rq],hv,wn4[i]);
                }
                float4 ov = *(const float4*)&hb[32];   // obs slice for this chunk
                acc4(pr[rq],ov,wr4[8]);
                acc4(pz[rq],ov,wz4[8]);
            }
            #pragma unroll
            for (int rq=0;rq<4;rq++){
                pr[rq] += __shfl_xor(pr[rq],1); pr[rq] += __shfl_xor(pr[rq],2);
                pz[rq] += __shfl_xor(pz[rq],1); pz[rq] += __shfl_xor(pz[rq],2);
                pn[rq] += __shfl_xor(pn[rq],1); pn[rq] += __shfl_xor(pn[rq],2);
            }
            // this thread finalizes row q*4+kc, output column j
            int rown = q*4 + kc;
            float spr = sel4(pr,kc), spz = sel4(pz,kc), spn = sel4(pn,kc);
            const float* rb = &hcur[rown*168];
            float4 o0 = *(const float4*)&rb[32];
            float4 o1 = *(const float4*)&rb[72];
            float4 o2 = *(const float4*)&rb[112];
            float4 o3 = *(const float4*)&rb[152];
            float gin = bcn; acc4(gin,o0,wcn[0]); acc4(gin,o1,wcn[1]); acc4(gin,o2,wcn[2]); acc4(gin,o3,wcn[3]);
            float ae  = baj; acc4(ae,o0,wap[0]);  acc4(ae,o1,wap[1]);  acc4(ae,o2,wap[2]);  acc4(ae,o3,wap[3]);
            float rg = 1.f/(1.f+expf(-(spr + bcrt)));
            float zg = 1.f/(1.f+expf(-(spz + bczt)));
            float ng = tanhf(fmaf(rg, spn + bhn, gin));
            float hold = rb[jaddr_off];
            float hn = fmaf(zg, hold-ng, ng);          // (1-z)n + z*h
            hnxt[rown*168 + jaddr_off]  = hn;
            air_s[rown*168 + jaddr_off] = hn + ae;
            if (s==63) out[(size_t)N_ + (size_t)(row0+rown)*128 + j] = hn;
        }
        __syncthreads();   // bar_1: P1 reads of hcur done; hnxt h-region + air_s written

        // ---- P3: coalesced air write + stage obs(s+1) into hnxt slots ----
        {
            int rr = t>>5, c0 = (t&31)*4;
            float4 av = *(const float4*)&air_s[caddr(rr,c0)];
            *(float4*)&air[((size_t)(row0+rr)*64 + s)*128 + c0] = av;
        }
        if (t<256){
            int rr = t>>4, c = t&15;
            int sn = (s<63) ? s+1 : s;   // last-step dummy, in-bounds
            hnxt[rr*168 + (c>>2)*40 + 32 + (c&3)] =
                (c<15) ? obs[((size_t)(row0+rr)*64 + sn)*15 + c] : 0.f;
        }
        __syncthreads();   // bar_2: hnxt complete before next P1
    }
}

// ---------------- Kernel B1: attention (per-token), in-place combined ----------------
__global__ __attribute__((amdgpu_waves_per_eu(4))) __launch_bounds__(512)
void attn_kernel(
    const float* __restrict__ obs, const float* __restrict__ wo,
    const float* __restrict__ bo,  const float* __restrict__ ws,
    float* __restrict__ air)
{
    __shared__ float X_s[16*168];
    __shared__ float ctx_s[16*168];
    __shared__ float comb_s[16*168];
    __shared__ float obs_m[16][8];
    __shared__ float part[16][2][8];
    __shared__ float attn_s[16][4][2];
    __shared__ float mu_s[16], rs_s[16];
    __shared__ float kmu_s[16][2], krs_s[16][2];
    __shared__ int   kmask_s[16][2];
    __shared__ int   bothm_s[16];

    const int t = threadIdx.x;
    const int j = t>>2, kc = t&3;
    const int w = t>>6;
    const int n0 = blockIdx.x*16;
    const int jaddr_off = (j>>5)*40 + (j&31);

    // weights in registers
    const float4* wqp4 = (const float4*)(ws + WS_WQP);
    const float4* wo4g = (const float4*)wo;
    float4 wq4[8], woo4[8];
    #pragma unroll
    for (int i=0;i<8;i++){ wq4[i] = wqp4[j*32 + kc*8 + i]; woo4[i] = wo4g[j*32 + kc*8 + i]; }
    const float sqj = ws[WS_SQ+j], eqj = ws[WS_EQ+j];
    const float4 kcj = ((const float4*)(ws+WS_KC))[j];
    const float ek1j = ws[WS_EK1+j], skj = ws[WS_SK+j], ek2j = ws[WS_EK2+j];
    const float4 vcj = ((const float4*)(ws+WS_VC))[j];
    const float vbj = ws[WS_VB+j];
    const float boj = bo[j];

    // stage X tile + LN stats + missile staging/stats
    {
        int rr = t>>5, c0 = (t&31)*4;
        float4 xv = *(const float4*)&air[(size_t)(n0+rr)*128 + c0];
        *(float4*)&X_s[caddr(rr,c0)] = xv;
        float sm = xv.x+xv.y+xv.z+xv.w;
        float s2 = fmaf(xv.x,xv.x, fmaf(xv.y,xv.y, fmaf(xv.z,xv.z, xv.w*xv.w)));
        #pragma unroll
        for (int m=1;m<32;m<<=1){ sm += __shfl_xor(sm,m); s2 += __shfl_xor(s2,m); }
        if ((t&31)==0){
            float mu = sm*(1.f/128.f);
            float var = s2*(1.f/128.f) - mu*mu;
            mu_s[rr]=mu; rs_s[rr]=rsqrtf(var+1e-5f);
        }
    }
    if (t>=128 && t<256){
        int idx = t-128; int rr = idx>>3, f = idx&7;
        obs_m[rr][f] = obs[(size_t)(n0+rr)*15 + f];
    }
    if (t<32){
        int rr = t&15, mi = t>>4;
        const float* mp = &obs[(size_t)(n0+rr)*15 + mi*4];
        float m0=mp[0], m1=mp[1], m2=mp[2], m3=mp[3];
        const float tol1 = 1e-8f + 1e-5f, tol0 = 1e-8f;
        kmask_s[rr][mi] = (fabsf(m0-1.f)<=tol1)&&(fabsf(m1)<=tol0)&&
                          (fabsf(m2-1.f)<=tol1)&&(fabsf(m3)<=tol0);
        float mv[4]={m0,m1,m2,m3};
        float mu = ws[WS_MBC];
        #pragma unroll
        for (int f=0;f<4;f++) mu = fmaf(ws[WS_MV+f], mv[f], mu);
        float e2 = ws[WS_C0];
        #pragma unroll
        for (int a4=0;a4<4;a4++){
            e2 = fmaf(ws[WS_QLIN+a4], mv[a4], e2);
            #pragma unroll
            for (int b4=0;b4<4;b4++) e2 = fmaf(ws[WS_QQ+a4*4+b4]*mv[a4], mv[b4], e2);
        }
        float var = e2 - mu*mu;
        kmu_s[rr][mi]=mu; krs_s[rr][mi]=rsqrtf(var+1e-5f);
    }
    __syncthreads();

    // q matvec: full dots via kc-butterfly; owner keeps rows 4kc..4kc+3
    float qown[4];
    #pragma unroll
    for (int r=0;r<16;r++){
        float acc = 0.f;
        const float* xb = &X_s[r*168 + kc*40];
        #pragma unroll
        for (int i=0;i<8;i++) acc4(acc, *(const float4*)&xb[i*4], wq4[i]);
        acc += __shfl_xor(acc,1); acc += __shfl_xor(acc,2);
        if (kc == (r>>2)) qown[r&3] = acc;
    }
    // scores: q*k products, reduce over 16 j within wave, stash per-wave partials
    #pragma unroll
    for (int oi=0;oi<4;oi++){
        int r = kc*4 + oi;
        float qv = fmaf(rs_s[r], qown[oi] - mu_s[r]*sqj, eqj);
        float4 m0v = *(const float4*)&obs_m[r][0];
        float4 m1v = *(const float4*)&obs_m[r][4];
        float k0 = fmaf(krs_s[r][0], dot4(kcj,m0v)+ek1j - kmu_s[r][0]*skj, ek2j);
        float k1 = fmaf(krs_s[r][1], dot4(kcj,m1v)+ek1j - kmu_s[r][1]*skj, ek2j);
        float p0 = qv*k0, p1 = qv*k1;
        #pragma unroll
        for (int m=4;m<64;m<<=1){ p0 += __shfl_xor(p0,m); p1 += __shfl_xor(p1,m); }
        if ((t&63)==kc){ part[r][0][w]=p0; part[r][1][w]=p1; }
    }
    __syncthreads();
    if (t<64){
        int rr = t&15, hd = t>>4;
        float s0 = part[rr][0][2*hd] + part[rr][0][2*hd+1];
        float s1 = part[rr][1][2*hd] + part[rr][1][2*hd+1];
        const float scale = 0.17677669529663687f;  // 1/sqrt(32)
        s0 *= scale; s1 *= scale;
        int m0 = kmask_s[rr][0], m1 = kmask_s[rr][1];
        float a0, a1;
        if (m0 && m1) { a0=0.f; a1=0.f; if (hd==0) bothm_s[rr]=1; }
        else {
            if (hd==0) bothm_s[rr]=0;
            if (m0)      { a0=0.f; a1=1.f; }
            else if (m1) { a0=1.f; a1=0.f; }
            else {
                float mx = fmaxf(s0,s1);
                float e0 = expf(s0-mx), e1 = expf(s1-mx);
                float inv = 1.f/(e0+e1);
                a0 = e0*inv; a1 = e1*inv;
            }
        }
        attn_s[rr][hd][0]=a0; attn_s[rr][hd][1]=a1;
    }
    __syncthreads();
    // ctx
    {
        int hd = j>>5;
        #pragma unroll
        for (int oi=0;oi<4;oi++){
            int r = kc*4 + oi;
            float4 m0v = *(const float4*)&obs_m[r][0];
            float4 m1v = *(const float4*)&obs_m[r][4];
            float v0 = dot4(vcj,m0v)+vbj, v1 = dot4(vcj,m1v)+vbj;
            ctx_s[r*168 + jaddr_off] = attn_s[r][hd][0]*v0 + attn_s[r][hd][1]*v1;
        }
    }
    __syncthreads();
    // attn_out matvec + nan guard + residual
    float aown[4];
    #pragma unroll
    for (int r=0;r<16;r++){
        float acc = 0.f;
        const float* zb = &ctx_s[r*168 + kc*40];
        #pragma unroll
        for (int i=0;i<8;i++) acc4(acc, *(const float4*)&zb[i*4], woo4[i]);
        acc += __shfl_xor(acc,1); acc += __shfl_xor(acc,2);
        if (kc == (r>>2)) aown[r&3] = acc;
    }
    #pragma unroll
    for (int oi=0;oi<4;oi++){
        int r = kc*4 + oi;
        float ao = bothm_s[r] ? 0.f : (aown[oi] + boj);
        comb_s[r*168 + jaddr_off] = X_s[r*168 + jaddr_off] + ao;
    }
    __syncthreads();
    // write combined back in place over air
    {
        int rr = t>>5, c0 = (t&31)*4;
        float4 cv = *(const float4*)&comb_s[caddr(rr,c0)];
        *(float4*)&air[(size_t)(n0+rr)*128 + c0] = cv;
    }
}

// ---------------- Kernel B2: MLP head ----------------
__global__ __attribute__((amdgpu_waves_per_eu(4))) __launch_bounds__(512)
void mlp_kernel(
    const float* __restrict__ comb,
    const float* __restrict__ w0, const float* __restrict__ b0,
    const float* __restrict__ w1, const float* __restrict__ b1,
    const float* __restrict__ fcw, const float* __restrict__ fcb,
    float* __restrict__ out)
{
    __shared__ float C_s[16*168];
    __shared__ float H_s[16*168];
    __shared__ float part2[16][8];

    const int t = threadIdx.x;
    const int j = t>>2, kc = t&3;
    const int w = t>>6;
    const int n0 = blockIdx.x*16;
    const int jaddr_off = (j>>5)*40 + (j&31);

    const float4* w04g = (const float4*)w0;
    const float4* w14g = (const float4*)w1;
    float4 w04[8], w14[8];
    #pragma unroll
    for (int i=0;i<8;i++){ w04[i] = w04g[j*32 + kc*8 + i]; w14[i] = w14g[j*32 + kc*8 + i]; }
    const float b0j = b0[j], b1j = b1[j], fcj = fcw[j];

    {
        int rr = t>>5, c0 = (t&31)*4;
        float4 cv = *(const float4*)&comb[(size_t)(n0+rr)*128 + c0];
        *(float4*)&C_s[caddr(rr,c0)] = cv;
    }
    __syncthreads();
    // mlp0
    float hown[4];
    #pragma unroll
    for (int r=0;r<16;r++){
        float acc = 0.f;
        const float* cb = &C_s[r*168 + kc*40];
        #pragma unroll
        for (int i=0;i<8;i++) acc4(acc, *(const float4*)&cb[i*4], w04[i]);
        acc += __shfl_xor(acc,1); acc += __shfl_xor(acc,2);
        if (kc == (r>>2)){
            float v = acc + b0j;
            hown[r&3] = (v > 0.f) ? v : 0.01f*v;
        }
    }
    #pragma unroll
    for (int oi=0;oi<4;oi++) H_s[(kc*4+oi)*168 + jaddr_off] = hown[oi];
    __syncthreads();
    // mlp1 + fco
    float pown[4];
    #pragma unroll
    for (int r=0;r<16;r++){
        float acc = 0.f;
        const float* hb = &H_s[r*168 + kc*40];
        #pragma unroll
        for (int i=0;i<8;i++) acc4(acc, *(const float4*)&hb[i*4], w14[i]);
        acc += __shfl_xor(acc,1); acc += __shfl_xor(acc,2);
        if (kc == (r>>2)){
            float v = acc + b1j;
            v = (v > 0.f) ? v : 0.01f*v;
            pown[r&3] = v * fcj;
        }
    }
    #pragma unroll
    for (int oi=0;oi<4;oi++){
        float p = pown[oi];
        #pragma unroll
        for (int m=4;m<64;m<<=1) p += __shfl_xor(p,m);
        if ((t&63)==kc) part2[kc*4+oi][w] = p;
    }
    __syncthreads();
    if (t<16){
        float a = 0.f;
        #pragma unroll
        for (int k=0;k<8;k++) a += part2[t][k];
        out[n0 + t] = a + fcb[0];
    }
}

extern "C" void kernel_launch(void* const* d_in, const int* in_sizes, int n_in,
                              void* d_out, int out_size, void* d_ws, size_t ws_size,
                              hipStream_t stream) {
    const float* obs       = (const float*)d_in[0];
    const float* h0        = (const float*)d_in[1];
    const float* enc_air_w = (const float*)d_in[2];
    const float* enc_air_b = (const float*)d_in[3];
    const float* enc_m_w   = (const float*)d_in[4];
    const float* enc_m_b   = (const float*)d_in[5];
    const float* gru_wih   = (const float*)d_in[6];
    const float* gru_whh   = (const float*)d_in[7];
    const float* gru_bih   = (const float*)d_in[8];
    const float* gru_bhh   = (const float*)d_in[9];
    const float* qln_w     = (const float*)d_in[10];
    const float* qln_b     = (const float*)d_in[11];
    const float* kln_w     = (const float*)d_in[12];
    const float* kln_b     = (const float*)d_in[13];
    const float* attn_in_w = (const float*)d_in[14];
    const float* attn_in_b = (const float*)d_in[15];
    const float* attn_out_w= (const float*)d_in[16];
    const float* attn_out_b= (const float*)d_in[17];
    const float* mlp0_w    = (const float*)d_in[18];
    const float* mlp0_b    = (const float*)d_in[19];
    const float* mlp1_w    = (const float*)d_in[20];
    const float* mlp1_b    = (const float*)d_in[21];
    const float* fco_w     = (const float*)d_in[22];
    const float* fco_b     = (const float*)d_in[23];
    float* out = (float*)d_out;
    float* ws  = (float*)d_ws;
    float* air = ws + WS_AIR;

    precompute_kernel<<<dim3(105), dim3(256), 0, stream>>>(
        enc_air_w, enc_air_b, enc_m_w, enc_m_b, gru_wih, gru_bih,
        qln_w, qln_b, kln_w, kln_b, attn_in_w, attn_in_b, ws);

    gru_kernel<<<dim3(256), dim3(512), 0, stream>>>(
        obs, h0, gru_whh, gru_bhh, enc_air_b, ws, air, out);

    attn_kernel<<<dim3(N_/16), dim3(512), 0, stream>>>(
        obs, attn_out_w, attn_out_b, ws, air);

    mlp_kernel<<<dim3(N_/16), dim3(512), 0, stream>>>(
        air, mlp0_w, mlp0_b, mlp1_w, mlp1_b, fco_w, fco_b, out);
}

// Round 4
// 3216.959 us; speedup vs baseline: 2.6866x; 2.6866x over previous
//
#include <hip/hip_runtime.h>
#include <math.h>

#define B_   4096
#define S_   64
#define H_   128
#define N_   (B_*S_)

// ---- workspace float offsets ----
#define WS_WC    0        // [384][16]  combined obs->gi weights (padded f=16)
#define WS_BC    6144     // [384]      combined gi bias
#define WS_WAP   6528     // [128][16]  padded enc_air_w
#define WS_WQP   8576     // [128][128] wq * qln_w (folded)
#define WS_SQ    24960    // [128] row sums of wqp
#define WS_EQ    25088    // [128] wq@qln_b + bq
#define WS_KC    25216    // [128][4]  (wk*klnw)@enc_m_w
#define WS_EK1   25728    // [128] (wk*klnw)@enc_m_b
#define WS_SK    25856    // [128] rowsum(wk*klnw)
#define WS_EK2   25984    // [128] wk@kln_b + bk
#define WS_VC    26112    // [128][4]  wv@enc_m_w
#define WS_VB    26624    // [128] wv@enc_m_b + bv
#define WS_MV    26752    // [4] mean weights for keys_raw mean
#define WS_QQ    26756    // [16] 4x4 quadratic form for E[y^2]
#define WS_QLIN  26772    // [4]
#define WS_MBC   26776
#define WS_C0    26777
#define WS_AIR   27392    // [N_][128] air_feat / combined buffer (in-place)

__device__ __forceinline__ float dot4(float4 a, float4 b){
    return fmaf(a.x,b.x, fmaf(a.y,b.y, fmaf(a.z,b.z, a.w*b.w)));
}
__device__ __forceinline__ void acc4(float& acc, float4 a, float4 b){
    acc = fmaf(a.x,b.x,acc); acc = fmaf(a.y,b.y,acc);
    acc = fmaf(a.z,b.z,acc); acc = fmaf(a.w,b.w,acc);
}
// attn/mlp chunked LDS addressing: row pitch 168, kc-chunk pitch 40
__device__ __forceinline__ int caddr(int r, int c){
    return r*168 + (c>>5)*40 + (c&31);
}

// ---------------- precompute folded weights ----------------
__global__ void precompute_kernel(
    const float* __restrict__ enc_air_w, const float* __restrict__ enc_air_b,
    const float* __restrict__ enc_m_w,  const float* __restrict__ enc_m_b,
    const float* __restrict__ gru_wih,  const float* __restrict__ gru_bih,
    const float* __restrict__ qln_w, const float* __restrict__ qln_b,
    const float* __restrict__ kln_w, const float* __restrict__ kln_b,
    const float* __restrict__ attn_in_w, const float* __restrict__ attn_in_b,
    float* __restrict__ ws)
{
    int i = blockIdx.x*blockDim.x + threadIdx.x;
    if (i < 6144) {                       // Wc[o][f] = sum_k wih[o][k]*Wa[k][f]
        int o = i>>4, f = i&15; float a = 0.f;
        if (f < 15) for (int k=0;k<128;k++) a = fmaf(gru_wih[o*128+k], enc_air_w[k*15+f], a);
        ws[WS_WC+i] = a;
    } else if (i < 6528) {                // bc
        int o = i-6144; float a = gru_bih[o];
        for (int k=0;k<128;k++) a = fmaf(gru_wih[o*128+k], enc_air_b[k], a);
        ws[WS_BC+o] = a;
    } else if (i < 8576) {                // Wap padded
        int idx = i-6528; int j = idx>>4, f = idx&15;
        ws[WS_WAP+idx] = (f<15) ? enc_air_w[j*15+f] : 0.f;
    } else if (i < 24960) {               // wqp
        int idx = i-8576; int o = idx>>7, j = idx&127;
        ws[WS_WQP+idx] = attn_in_w[o*128+j]*qln_w[j];
    } else if (i < 25088) {               // sq
        int o = i-24960; float a=0.f;
        for (int j=0;j<128;j++) a = fmaf(attn_in_w[o*128+j], qln_w[j], a);
        ws[WS_SQ+o]=a;
    } else if (i < 25216) {               // eq
        int o = i-25088; float a = attn_in_b[o];
        for (int j=0;j<128;j++) a = fmaf(attn_in_w[o*128+j], qln_b[j], a);
        ws[WS_EQ+o]=a;
    } else if (i < 25728) {               // Kc
        int idx = i-25216; int o = idx>>2, f = idx&3; float a=0.f;
        for (int j=0;j<128;j++) a = fmaf(attn_in_w[(128+o)*128+j]*kln_w[j], enc_m_w[j*4+f], a);
        ws[WS_KC+idx]=a;
    } else if (i < 25856) {               // ek1
        int o = i-25728; float a=0.f;
        for (int j=0;j<128;j++) a = fmaf(attn_in_w[(128+o)*128+j]*kln_w[j], enc_m_b[j], a);
        ws[WS_EK1+o]=a;
    } else if (i < 25984) {               // sk
        int o = i-25856; float a=0.f;
        for (int j=0;j<128;j++) a = fmaf(attn_in_w[(128+o)*128+j], kln_w[j], a);
        ws[WS_SK+o]=a;
    } else if (i < 26112) {               // ek2
        int o = i-25984; float a = attn_in_b[128+o];
        for (int j=0;j<128;j++) a = fmaf(attn_in_w[(128+o)*128+j], kln_b[j], a);
        ws[WS_EK2+o]=a;
    } else if (i < 26624) {               // Vc
        int idx = i-26112; int o = idx>>2, f = idx&3; float a=0.f;
        for (int j=0;j<128;j++) a = fmaf(attn_in_w[(256+o)*128+j], enc_m_w[j*4+f], a);
        ws[WS_VC+idx]=a;
    } else if (i < 26752) {               // vb
        int o = i-26624; float a = attn_in_b[256+o];
        for (int j=0;j<128;j++) a = fmaf(attn_in_w[(256+o)*128+j], enc_m_b[j], a);
        ws[WS_VB+o]=a;
    } else if (i < 26756) {               // Mv
        int f = i-26752; float a=0.f;
        for (int j=0;j<128;j++) a += enc_m_w[j*4+f];
        ws[WS_MV+f]=a*(1.f/128.f);
    } else if (i < 26772) {               // QQ
        int idx = i-26756; int a4 = idx>>2, b4 = idx&3; float a=0.f;
        for (int j=0;j<128;j++) a = fmaf(enc_m_w[j*4+a4], enc_m_w[j*4+b4], a);
        ws[WS_QQ+idx]=a*(1.f/128.f);
    } else if (i < 26776) {               // qlin
        int f = i-26772; float a=0.f;
        for (int j=0;j<128;j++) a = fmaf(enc_m_b[j], enc_m_w[j*4+f], a);
        ws[WS_QLIN+f]=a*(2.f/128.f);
    } else if (i == 26776) {
        float a=0.f; for (int j=0;j<128;j++) a += enc_m_b[j];
        ws[WS_MBC]=a*(1.f/128.f);
    } else if (i == 26777) {
        float a=0.f; for (int j=0;j<128;j++) a = fmaf(enc_m_b[j], enc_m_b[j], a);
        ws[WS_C0]=a*(1.f/128.f);
    }
}

// ---------------- Kernel A: GRU ----------------
// 256 blocks x 16 rows x 1024 threads. Thread (j=t>>3, kc=t&7) owns 16-float
// whh chunks for 3 gates (48 regs) + 4 obs-fold floats. Wc_n/Wap rows in LDS.
// Dots reduced via shfl_xor over the kc octet; every lane finalizes rows {kc, kc+8}.
// Fits the natural 128-VGPR cap of 16-wave blocks -> no spills.
__global__ __launch_bounds__(1024) void gru_kernel(
    const float* __restrict__ obs, const float* __restrict__ h0,
    const float* __restrict__ whh, const float* __restrict__ bhh,
    const float* __restrict__ ba,  const float* __restrict__ ws,
    float* __restrict__ air, float* __restrict__ out)
{
    __shared__ float h_s[2][16*164];   // chunk pitch 20 (banks 20kc%32 distinct), row pitch 164
    __shared__ float obs_s[16*20];     // row pitch 20
    __shared__ float air_s[16*132];
    __shared__ float wn_s[128*20];     // Wc_n rows, pitch 20
    __shared__ float wap_s[128*20];    // Wap rows, pitch 20

    const int t  = threadIdx.x;
    const int j  = t>>3;        // 0..127 output column
    const int kc = t&7;         // 0..7 k-chunk
    const int row0 = blockIdx.x*16;

    // --- persistent weights: 48 + 4 floats ---
    const float4* whh4 = (const float4*)whh;
    float4 whr[4], whz[4], whn[4];
    #pragma unroll
    for (int i=0;i<4;i++){
        whr[i] = whh4[(      j)*32 + kc*4 + i];
        whz[i] = whh4[(128 + j)*32 + kc*4 + i];
        whn[i] = whh4[(256 + j)*32 + kc*4 + i];
    }
    const float wro0 = ws[WS_WC + j*16 + 2*kc];
    const float wro1 = ws[WS_WC + j*16 + 2*kc+1];
    const float wzo0 = ws[WS_WC + (128+j)*16 + 2*kc];
    const float wzo1 = ws[WS_WC + (128+j)*16 + 2*kc+1];
    const float bcrt = ws[WS_BC+j]     + bhh[j];
    const float bczt = ws[WS_BC+128+j] + bhh[128+j];
    const float bcn  = ws[WS_BC+256+j];
    const float bhn  = bhh[256+j];
    const float baj  = ba[j];
    const int hoff_j = (j>>4)*20 + (j&15);

    // --- stage Wc_n / Wap into LDS ---
    {
        int f = t&15, jr = t>>4;   // jr 0..63
        wn_s [jr*20+f]      = ws[WS_WC + (256+jr)*16 + f];
        wn_s [(jr+64)*20+f] = ws[WS_WC + (256+jr+64)*16 + f];
        wap_s[jr*20+f]      = ws[WS_WAP + jr*16 + f];
        wap_s[(jr+64)*20+f] = ws[WS_WAP + (jr+64)*16 + f];
    }
    // --- stage h0 + obs(0) ---
    if (t < 512){
        int rr = t>>5, c0 = (t&31)*4;
        float4 hv = *(const float4*)&h0[(size_t)(row0+rr)*128 + c0];
        *(float4*)&h_s[0][rr*164 + (c0>>4)*20 + (c0&15)] = hv;
    }
    if (t < 256){
        int rr = t>>4, c = t&15;
        obs_s[rr*20+c] = (c<15) ? obs[((size_t)(row0+rr)*64 + 0)*15 + c] : 0.f;
    }
    __syncthreads();

    for (int s=0;s<64;s++){
        const float* hcur = h_s[s&1];
        float*       hnxt = h_s[(s+1)&1];

        float sAr=0.f,sAz=0.f,sAn=0.f, sBr=0.f,sBz=0.f,sBn=0.f;
        #pragma unroll
        for (int p=0;p<8;p++){
            const int r0=2*p, r1=2*p+1;
            float pr0=0.f,pz0=0.f,pn0=0.f, pr1=0.f,pz1=0.f,pn1=0.f;
            {
                const float* hb = &hcur[r0*164 + kc*20];
                #pragma unroll
                for (int i=0;i<4;i++){
                    float4 hv = *(const float4*)&hb[i*4];
                    acc4(pr0,hv,whr[i]); acc4(pz0,hv,whz[i]); acc4(pn0,hv,whn[i]);
                }
                float o0 = obs_s[r0*20+2*kc], o1 = obs_s[r0*20+2*kc+1];
                pr0 = fmaf(o0,wro0, fmaf(o1,wro1, pr0));
                pz0 = fmaf(o0,wzo0, fmaf(o1,wzo1, pz0));
            }
            {
                const float* hb = &hcur[r1*164 + kc*20];
                #pragma unroll
                for (int i=0;i<4;i++){
                    float4 hv = *(const float4*)&hb[i*4];
                    acc4(pr1,hv,whr[i]); acc4(pz1,hv,whz[i]); acc4(pn1,hv,whn[i]);
                }
                float o0 = obs_s[r1*20+2*kc], o1 = obs_s[r1*20+2*kc+1];
                pr1 = fmaf(o0,wro0, fmaf(o1,wro1, pr1));
                pz1 = fmaf(o0,wzo0, fmaf(o1,wzo1, pz1));
            }
            // reduce over kc octet (lanes differ in bits 0..2)
            pr0 += __shfl_xor(pr0,1); pr0 += __shfl_xor(pr0,2); pr0 += __shfl_xor(pr0,4);
            pz0 += __shfl_xor(pz0,1); pz0 += __shfl_xor(pz0,2); pz0 += __shfl_xor(pz0,4);
            pn0 += __shfl_xor(pn0,1); pn0 += __shfl_xor(pn0,2); pn0 += __shfl_xor(pn0,4);
            pr1 += __shfl_xor(pr1,1); pr1 += __shfl_xor(pr1,2); pr1 += __shfl_xor(pr1,4);
            pz1 += __shfl_xor(pz1,1); pz1 += __shfl_xor(pz1,2); pz1 += __shfl_xor(pz1,4);
            pn1 += __shfl_xor(pn1,1); pn1 += __shfl_xor(pn1,2); pn1 += __shfl_xor(pn1,4);
            // latch: lane kc keeps rows {kc, kc+8}
            if ((r0&7)==kc){ if (r0<8){sAr=pr0;sAz=pz0;sAn=pn0;} else {sBr=pr0;sBz=pz0;sBn=pn0;} }
            if ((r1&7)==kc){ if (r1<8){sAr=pr1;sAz=pz1;sAn=pn1;} else {sBr=pr1;sBz=pz1;sBn=pn1;} }
        }

        // ---- finalize rows kc and kc+8 (all lanes in parallel) ----
        #pragma unroll
        for (int u=0;u<2;u++){
            const int r = kc + 8*u;
            float sr = u ? sBr : sAr;
            float sz = u ? sBz : sAz;
            float sn = u ? sBn : sAn;
            const float* ob = &obs_s[r*20];
            float4 o0 = *(const float4*)&ob[0],  o1 = *(const float4*)&ob[4];
            float4 o2 = *(const float4*)&ob[8],  o3 = *(const float4*)&ob[12];
            float gin = bcn;
            gin = fmaf(1.f,0.f,gin);
            acc4(gin,o0,*(const float4*)&wn_s[j*20+ 0]);
            acc4(gin,o1,*(const float4*)&wn_s[j*20+ 4]);
            acc4(gin,o2,*(const float4*)&wn_s[j*20+ 8]);
            acc4(gin,o3,*(const float4*)&wn_s[j*20+12]);
            float ae = baj;
            acc4(ae,o0,*(const float4*)&wap_s[j*20+ 0]);
            acc4(ae,o1,*(const float4*)&wap_s[j*20+ 4]);
            acc4(ae,o2,*(const float4*)&wap_s[j*20+ 8]);
            acc4(ae,o3,*(const float4*)&wap_s[j*20+12]);
            float rg = 1.f/(1.f+__expf(-(sr+bcrt)));
            float zg = 1.f/(1.f+__expf(-(sz+bczt)));
            float nx = fmaf(rg, sn + bhn, gin);
            float e2 = __expf(2.f*nx);
            float ng = 1.f - 2.f/(e2+1.f);          // tanh(nx)
            float hold = hcur[r*164 + hoff_j];
            float hn = fmaf(zg, hold-ng, ng);       // (1-z)n + z*h
            hnxt[r*164 + hoff_j] = hn;
            air_s[r*132 + j] = hn + ae;
            if (s==63) out[(size_t)N_ + (size_t)(row0+r)*128 + j] = hn;
        }
        __syncthreads();   // bar_1: hcur/obs reads done; hnxt/air_s written

        // ---- coalesced air write + stage obs(s+1) ----
        if (t < 512){
            int rr = t>>5, c0 = (t&31)*4;
            float4 av = *(const float4*)&air_s[rr*132 + c0];
            *(float4*)&air[((size_t)(row0+rr)*64 + s)*128 + c0] = av;
        }
        if (s<63 && t<256){
            int rr = t>>4, c = t&15;
            obs_s[rr*20+c] = (c<15) ? obs[((size_t)(row0+rr)*64 + (s+1))*15 + c] : 0.f;
        }
        __syncthreads();   // bar_2
    }
}

// ---------------- Kernel B1: attention (per-token), in-place combined ----------------
__global__ __launch_bounds__(512) void attn_kernel(
    const float* __restrict__ obs, const float* __restrict__ wo,
    const float* __restrict__ bo,  const float* __restrict__ ws,
    float* __restrict__ air)
{
    __shared__ float X_s[16*168];
    __shared__ float ctx_s[16*168];
    __shared__ float comb_s[16*168];
    __shared__ float obs_m[16][8];
    __shared__ float part[16][2][8];
    __shared__ float attn_s[16][4][2];
    __shared__ float mu_s[16], rs_s[16];
    __shared__ float kmu_s[16][2], krs_s[16][2];
    __shared__ int   kmask_s[16][2];
    __shared__ int   bothm_s[16];

    const int t = threadIdx.x;
    const int j = t>>2, kc = t&3;
    const int w = t>>6;
    const int n0 = blockIdx.x*16;
    const int jaddr_off = (j>>5)*40 + (j&31);

    // weights in registers
    const float4* wqp4 = (const float4*)(ws + WS_WQP);
    const float4* wo4g = (const float4*)wo;
    float4 wq4[8], woo4[8];
    #pragma unroll
    for (int i=0;i<8;i++){ wq4[i] = wqp4[j*32 + kc*8 + i]; woo4[i] = wo4g[j*32 + kc*8 + i]; }
    const float sqj = ws[WS_SQ+j], eqj = ws[WS_EQ+j];
    const float4 kcj = ((const float4*)(ws+WS_KC))[j];
    const float ek1j = ws[WS_EK1+j], skj = ws[WS_SK+j], ek2j = ws[WS_EK2+j];
    const float4 vcj = ((const float4*)(ws+WS_VC))[j];
    const float vbj = ws[WS_VB+j];
    const float boj = bo[j];

    // stage X tile + LN stats + missile staging/stats
    {
        int rr = t>>5, c0 = (t&31)*4;
        float4 xv = *(const float4*)&air[(size_t)(n0+rr)*128 + c0];
        *(float4*)&X_s[caddr(rr,c0)] = xv;
        float sm = xv.x+xv.y+xv.z+xv.w;
        float s2 = fmaf(xv.x,xv.x, fmaf(xv.y,xv.y, fmaf(xv.z,xv.z, xv.w*xv.w)));
        #pragma unroll
        for (int m=1;m<32;m<<=1){ sm += __shfl_xor(sm,m); s2 += __shfl_xor(s2,m); }
        if ((t&31)==0){
            float mu = sm*(1.f/128.f);
            float var = s2*(1.f/128.f) - mu*mu;
            mu_s[rr]=mu; rs_s[rr]=rsqrtf(var+1e-5f);
        }
    }
    if (t>=128 && t<256){
        int idx = t-128; int rr = idx>>3, f = idx&7;
        obs_m[rr][f] = obs[(size_t)(n0+rr)*15 + f];
    }
    if (t<32){
        int rr = t&15, mi = t>>4;
        const float* mp = &obs[(size_t)(n0+rr)*15 + mi*4];
        float m0=mp[0], m1=mp[1], m2=mp[2], m3=mp[3];
        const float tol1 = 1e-8f + 1e-5f, tol0 = 1e-8f;
        kmask_s[rr][mi] = (fabsf(m0-1.f)<=tol1)&&(fabsf(m1)<=tol0)&&
                          (fabsf(m2-1.f)<=tol1)&&(fabsf(m3)<=tol0);
        float mv[4]={m0,m1,m2,m3};
        float mu = ws[WS_MBC];
        #pragma unroll
        for (int f=0;f<4;f++) mu = fmaf(ws[WS_MV+f], mv[f], mu);
        float e2 = ws[WS_C0];
        #pragma unroll
        for (int a4=0;a4<4;a4++){
            e2 = fmaf(ws[WS_QLIN+a4], mv[a4], e2);
            #pragma unroll
            for (int b4=0;b4<4;b4++) e2 = fmaf(ws[WS_QQ+a4*4+b4]*mv[a4], mv[b4], e2);
        }
        float var = e2 - mu*mu;
        kmu_s[rr][mi]=mu; krs_s[rr][mi]=rsqrtf(var+1e-5f);
    }
    __syncthreads();

    // q matvec: full dots via kc-butterfly; owner keeps rows 4kc..4kc+3
    float qown[4];
    #pragma unroll
    for (int r=0;r<16;r++){
        float acc = 0.f;
        const float* xb = &X_s[r*168 + kc*40];
        #pragma unroll
        for (int i=0;i<8;i++) acc4(acc, *(const float4*)&xb[i*4], wq4[i]);
        acc += __shfl_xor(acc,1); acc += __shfl_xor(acc,2);
        if (kc == (r>>2)) qown[r&3] = acc;
    }
    // scores: q*k products, reduce over 16 j within wave, stash per-wave partials
    #pragma unroll
    for (int oi=0;oi<4;oi++){
        int r = kc*4 + oi;
        float qv = fmaf(rs_s[r], qown[oi] - mu_s[r]*sqj, eqj);
        float4 m0v = *(const float4*)&obs_m[r][0];
        float4 m1v = *(const float4*)&obs_m[r][4];
        float k0 = fmaf(krs_s[r][0], dot4(kcj,m0v)+ek1j - kmu_s[r][0]*skj, ek2j);
        float k1 = fmaf(krs_s[r][1], dot4(kcj,m1v)+ek1j - kmu_s[r][1]*skj, ek2j);
        float p0 = qv*k0, p1 = qv*k1;
        #pragma unroll
        for (int m=4;m<64;m<<=1){ p0 += __shfl_xor(p0,m); p1 += __shfl_xor(p1,m); }
        if ((t&63)==kc){ part[r][0][w]=p0; part[r][1][w]=p1; }
    }
    __syncthreads();
    if (t<64){
        int rr = t&15, hd = t>>4;
        float s0 = part[rr][0][2*hd] + part[rr][0][2*hd+1];
        float s1 = part[rr][1][2*hd] + part[rr][1][2*hd+1];
        const float scale = 0.17677669529663687f;  // 1/sqrt(32)
        s0 *= scale; s1 *= scale;
        int m0 = kmask_s[rr][0], m1 = kmask_s[rr][1];
        float a0, a1;
        if (m0 && m1) { a0=0.f; a1=0.f; if (hd==0) bothm_s[rr]=1; }
        else {
            if (hd==0) bothm_s[rr]=0;
            if (m0)      { a0=0.f; a1=1.f; }
            else if (m1) { a0=1.f; a1=0.f; }
            else {
                float mx = fmaxf(s0,s1);
                float e0 = __expf(s0-mx), e1 = __expf(s1-mx);
                float inv = 1.f/(e0+e1);
                a0 = e0*inv; a1 = e1*inv;
            }
        }
        attn_s[rr][hd][0]=a0; attn_s[rr][hd][1]=a1;
    }
    __syncthreads();
    // ctx
    {
        int hd = j>>5;
        #pragma unroll
        for (int oi=0;oi<4;oi++){
            int r = kc*4 + oi;
            float4 m0v = *(const float4*)&obs_m[r][0];
            float4 m1v = *(const float4*)&obs_m[r][4];
            float v0 = dot4(vcj,m0v)+vbj, v1 = dot4(vcj,m1v)+vbj;
            ctx_s[r*168 + jaddr_off] = attn_s[r][hd][0]*v0 + attn_s[r][hd][1]*v1;
        }
    }
    __syncthreads();
    // attn_out matvec + nan guard + residual
    float aown[4];
    #pragma unroll
    for (int r=0;r<16;r++){
        float acc = 0.f;
        const float* zb = &ctx_s[r*168 + kc*40];
        #pragma unroll
        for (int i=0;i<8;i++) acc4(acc, *(const float4*)&zb[i*4], woo4[i]);
        acc += __shfl_xor(acc,1); acc += __shfl_xor(acc,2);
        if (kc == (r>>2)) aown[r&3] = acc;
    }
    #pragma unroll
    for (int oi=0;oi<4;oi++){
        int r = kc*4 + oi;
        float ao = bothm_s[r] ? 0.f : (aown[oi] + boj);
        comb_s[r*168 + jaddr_off] = X_s[r*168 + jaddr_off] + ao;
    }
    __syncthreads();
    // write combined back in place over air
    {
        int rr = t>>5, c0 = (t&31)*4;
        float4 cv = *(const float4*)&comb_s[caddr(rr,c0)];
        *(float4*)&air[(size_t)(n0+rr)*128 + c0] = cv;
    }
}

// ---------------- Kernel B2: MLP head ----------------
__global__ __launch_bounds__(512) void mlp_kernel(
    const float* __restrict__ comb,
    const float* __restrict__ w0, const float* __restrict__ b0,
    const float* __restrict__ w1, const float* __restrict__ b1,
    const float* __restrict__ fcw, const float* __restrict__ fcb,
    float* __restrict__ out)
{
    __shared__ float C_s[16*168];
    __shared__ float H_s[16*168];
    __shared__ float part2[16][8];

    const int t = threadIdx.x;
    const int j = t>>2, kc = t&3;
    const int w = t>>6;
    const int n0 = blockIdx.x*16;
    const int jaddr_off = (j>>5)*40 + (j&31);

    const float4* w04g = (const float4*)w0;
    const float4* w14g = (const float4*)w1;
    float4 w04[8], w14[8];
    #pragma unroll
    for (int i=0;i<8;i++){ w04[i] = w04g[j*32 + kc*8 + i]; w14[i] = w14g[j*32 + kc*8 + i]; }
    const float b0j = b0[j], b1j = b1[j], fcj = fcw[j];

    {
        int rr = t>>5, c0 = (t&31)*4;
        float4 cv = *(const float4*)&comb[(size_t)(n0+rr)*128 + c0];
        *(float4*)&C_s[caddr(rr,c0)] = cv;
    }
    __syncthreads();
    // mlp0
    float hown[4];
    #pragma unroll
    for (int r=0;r<16;r++){
        float acc = 0.f;
        const float* cb = &C_s[r*168 + kc*40];
        #pragma unroll
        for (int i=0;i<8;i++) acc4(acc, *(const float4*)&cb[i*4], w04[i]);
        acc += __shfl_xor(acc,1); acc += __shfl_xor(acc,2);
        if (kc == (r>>2)){
            float v = acc + b0j;
            hown[r&3] = (v > 0.f) ? v : 0.01f*v;
        }
    }
    #pragma unroll
    for (int oi=0;oi<4;oi++) H_s[(kc*4+oi)*168 + jaddr_off] = hown[oi];
    __syncthreads();
    // mlp1 + fco
    float pown[4];
    #pragma unroll
    for (int r=0;r<16;r++){
        float acc = 0.f;
        const float* hb = &H_s[r*168 + kc*40];
        #pragma unroll
        for (int i=0;i<8;i++) acc4(acc, *(const float4*)&hb[i*4], w14[i]);
        acc += __shfl_xor(acc,1); acc += __shfl_xor(acc,2);
        if (kc == (r>>2)){
            float v = acc + b1j;
            v = (v > 0.f) ? v : 0.01f*v;
            pown[r&3] = v * fcj;
        }
    }
    #pragma unroll
    for (int oi=0;oi<4;oi++){
        float p = pown[oi];
        #pragma unroll
        for (int m=4;m<64;m<<=1) p += __shfl_xor(p,m);
        if ((t&63)==kc) part2[kc*4+oi][w] = p;
    }
    __syncthreads();
    if (t<16){
        float a = 0.f;
        #pragma unroll
        for (int k=0;k<8;k++) a += part2[t][k];
        out[n0 + t] = a + fcb[0];
    }
}

extern "C" void kernel_launch(void* const* d_in, const int* in_sizes, int n_in,
                              void* d_out, int out_size, void* d_ws, size_t ws_size,
                              hipStream_t stream) {
    const float* obs       = (const float*)d_in[0];
    const float* h0        = (const float*)d_in[1];
    const float* enc_air_w = (const float*)d_in[2];
    const float* enc_air_b = (const float*)d_in[3];
    const float* enc_m_w   = (const float*)d_in[4];
    const float* enc_m_b   = (const float*)d_in[5];
    const float* gru_wih   = (const float*)d_in[6];
    const float* gru_whh   = (const float*)d_in[7];
    const float* gru_bih   = (const float*)d_in[8];
    const float* gru_bhh   = (const float*)d_in[9];
    const float* qln_w     = (const float*)d_in[10];
    const float* qln_b     = (const float*)d_in[11];
    const float* kln_w     = (const float*)d_in[12];
    const float* kln_b     = (const float*)d_in[13];
    const float* attn_in_w = (const float*)d_in[14];
    const float* attn_in_b = (const float*)d_in[15];
    const float* attn_out_w= (const float*)d_in[16];
    const float* attn_out_b= (const float*)d_in[17];
    const float* mlp0_w    = (const float*)d_in[18];
    const float* mlp0_b    = (const float*)d_in[19];
    const float* mlp1_w    = (const float*)d_in[20];
    const float* mlp1_b    = (const float*)d_in[21];
    const float* fco_w     = (const float*)d_in[22];
    const float* fco_b     = (const float*)d_in[23];
    float* out = (float*)d_out;
    float* ws  = (float*)d_ws;
    float* air = ws + WS_AIR;

    precompute_kernel<<<dim3(105), dim3(256), 0, stream>>>(
        enc_air_w, enc_air_b, enc_m_w, enc_m_b, gru_wih, gru_bih,
        qln_w, qln_b, kln_w, kln_b, attn_in_w, attn_in_b, ws);

    gru_kernel<<<dim3(256), dim3(1024), 0, stream>>>(
        obs, h0, gru_whh, gru_bhh, enc_air_b, ws, air, out);

    attn_kernel<<<dim3(N_/16), dim3(512), 0, stream>>>(
        obs, attn_out_w, attn_out_b, ws, air);

    mlp_kernel<<<dim3(N_/16), dim3(512), 0, stream>>>(
        air, mlp0_w, mlp0_b, mlp1_w, mlp1_b, fco_w, fco_b, out);
}

// Round 5
// 3203.387 us; speedup vs baseline: 2.6980x; 1.0042x over previous
//
#include <hip/hip_runtime.h>
#include <math.h>

#define B_   4096
#define S_   64
#define H_   128
#define N_   (B_*S_)

// ---- workspace float offsets ----
#define WS_WC    0        // [384][16]  combined obs->gi weights (padded f=16)
#define WS_BC    6144     // [384]      combined gi bias
#define WS_WAP   6528     // [128][16]  padded enc_air_w
#define WS_WQP   8576     // [128][128] wq * qln_w (folded)
#define WS_SQ    24960    // [128] row sums of wqp
#define WS_EQ    25088    // [128] wq@qln_b + bq
#define WS_KC    25216    // [128][4]  (wk*klnw)@enc_m_w
#define WS_EK1   25728    // [128] (wk*klnw)@enc_m_b
#define WS_SK    25856    // [128] rowsum(wk*klnw)
#define WS_EK2   25984    // [128] wk@kln_b + bk
#define WS_VC    26112    // [128][4]  wv@enc_m_w
#define WS_VB    26624    // [128] wv@enc_m_b + bv
#define WS_MV    26752    // [4] mean weights for keys_raw mean
#define WS_QQ    26756    // [16] 4x4 quadratic form for E[y^2]
#define WS_QLIN  26772    // [4]
#define WS_MBC   26776
#define WS_C0    26777
#define WS_AIR   27392    // [N_][128] air_feat / combined buffer (in-place)

#define AP 172   // attn/mlp row pitch: 4*172%32==16 -> kc-dependent banks, <=2-way (free)

__device__ __forceinline__ float dot4(float4 a, float4 b){
    return fmaf(a.x,b.x, fmaf(a.y,b.y, fmaf(a.z,b.z, a.w*b.w)));
}
__device__ __forceinline__ void acc4(float& acc, float4 a, float4 b){
    acc = fmaf(a.x,b.x,acc); acc = fmaf(a.y,b.y,acc);
    acc = fmaf(a.z,b.z,acc); acc = fmaf(a.w,b.w,acc);
}
// attn/mlp chunked LDS addressing: row pitch AP, kc-chunk pitch 40
__device__ __forceinline__ int caddr(int r, int c){
    return r*AP + (c>>5)*40 + (c&31);
}

// ---------------- precompute folded weights ----------------
__global__ void precompute_kernel(
    const float* __restrict__ enc_air_w, const float* __restrict__ enc_air_b,
    const float* __restrict__ enc_m_w,  const float* __restrict__ enc_m_b,
    const float* __restrict__ gru_wih,  const float* __restrict__ gru_bih,
    const float* __restrict__ qln_w, const float* __restrict__ qln_b,
    const float* __restrict__ kln_w, const float* __restrict__ kln_b,
    const float* __restrict__ attn_in_w, const float* __restrict__ attn_in_b,
    float* __restrict__ ws)
{
    int i = blockIdx.x*blockDim.x + threadIdx.x;
    if (i < 6144) {                       // Wc[o][f] = sum_k wih[o][k]*Wa[k][f]
        int o = i>>4, f = i&15; float a = 0.f;
        if (f < 15) for (int k=0;k<128;k++) a = fmaf(gru_wih[o*128+k], enc_air_w[k*15+f], a);
        ws[WS_WC+i] = a;
    } else if (i < 6528) {                // bc
        int o = i-6144; float a = gru_bih[o];
        for (int k=0;k<128;k++) a = fmaf(gru_wih[o*128+k], enc_air_b[k], a);
        ws[WS_BC+o] = a;
    } else if (i < 8576) {                // Wap padded
        int idx = i-6528; int j = idx>>4, f = idx&15;
        ws[WS_WAP+idx] = (f<15) ? enc_air_w[j*15+f] : 0.f;
    } else if (i < 24960) {               // wqp
        int idx = i-8576; int o = idx>>7, j = idx&127;
        ws[WS_WQP+idx] = attn_in_w[o*128+j]*qln_w[j];
    } else if (i < 25088) {               // sq
        int o = i-24960; float a=0.f;
        for (int j=0;j<128;j++) a = fmaf(attn_in_w[o*128+j], qln_w[j], a);
        ws[WS_SQ+o]=a;
    } else if (i < 25216) {               // eq
        int o = i-25088; float a = attn_in_b[o];
        for (int j=0;j<128;j++) a = fmaf(attn_in_w[o*128+j], qln_b[j], a);
        ws[WS_EQ+o]=a;
    } else if (i < 25728) {               // Kc
        int idx = i-25216; int o = idx>>2, f = idx&3; float a=0.f;
        for (int j=0;j<128;j++) a = fmaf(attn_in_w[(128+o)*128+j]*kln_w[j], enc_m_w[j*4+f], a);
        ws[WS_KC+idx]=a;
    } else if (i < 25856) {               // ek1
        int o = i-25728; float a=0.f;
        for (int j=0;j<128;j++) a = fmaf(attn_in_w[(128+o)*128+j]*kln_w[j], enc_m_b[j], a);
        ws[WS_EK1+o]=a;
    } else if (i < 25984) {               // sk
        int o = i-25856; float a=0.f;
        for (int j=0;j<128;j++) a = fmaf(attn_in_w[(128+o)*128+j], kln_w[j], a);
        ws[WS_SK+o]=a;
    } else if (i < 26112) {               // ek2
        int o = i-25984; float a = attn_in_b[128+o];
        for (int j=0;j<128;j++) a = fmaf(attn_in_w[(128+o)*128+j], kln_b[j], a);
        ws[WS_EK2+o]=a;
    } else if (i < 26624) {               // Vc
        int idx = i-26112; int o = idx>>2, f = idx&3; float a=0.f;
        for (int j=0;j<128;j++) a = fmaf(attn_in_w[(256+o)*128+j], enc_m_w[j*4+f], a);
        ws[WS_VC+idx]=a;
    } else if (i < 26752) {               // vb
        int o = i-26624; float a = attn_in_b[256+o];
        for (int j=0;j<128;j++) a = fmaf(attn_in_w[(256+o)*128+j], enc_m_b[j], a);
        ws[WS_VB+o]=a;
    } else if (i < 26756) {               // Mv
        int f = i-26752; float a=0.f;
        for (int j=0;j<128;j++) a += enc_m_w[j*4+f];
        ws[WS_MV+f]=a*(1.f/128.f);
    } else if (i < 26772) {               // QQ
        int idx = i-26756; int a4 = idx>>2, b4 = idx&3; float a=0.f;
        for (int j=0;j<128;j++) a = fmaf(enc_m_w[j*4+a4], enc_m_w[j*4+b4], a);
        ws[WS_QQ+idx]=a*(1.f/128.f);
    } else if (i < 26776) {               // qlin
        int f = i-26772; float a=0.f;
        for (int j=0;j<128;j++) a = fmaf(enc_m_b[j], enc_m_w[j*4+f], a);
        ws[WS_QLIN+f]=a*(2.f/128.f);
    } else if (i == 26776) {
        float a=0.f; for (int j=0;j<128;j++) a += enc_m_b[j];
        ws[WS_MBC]=a*(1.f/128.f);
    } else if (i == 26777) {
        float a=0.f; for (int j=0;j<128;j++) a = fmaf(enc_m_b[j], enc_m_b[j], a);
        ws[WS_C0]=a*(1.f/128.f);
    }
}

// ---------------- Kernel A: GRU ----------------
// 256 blocks x 16 rows x 1024 threads. Thread (j=t>>3, kc=t&7) owns 16-float
// whh chunks for 3 gates (48 regs) + 4 obs-fold floats. Wc_n/Wap rows in LDS.
// __launch_bounds__(1024,1): min-waves 1 -> VGPR cap = launchability bound 128.
__global__ __launch_bounds__(1024,1) void gru_kernel(
    const float* __restrict__ obs, const float* __restrict__ h0,
    const float* __restrict__ whh, const float* __restrict__ bhh,
    const float* __restrict__ ba,  const float* __restrict__ ws,
    float* __restrict__ air, float* __restrict__ out)
{
    __shared__ float h_s[2][16*164];   // chunk pitch 20 (banks 20kc%32 distinct), row pitch 164
    __shared__ float obs_s[16*20];     // row pitch 20
    __shared__ float air_s[16*132];
    __shared__ float wn_s[128*20];     // Wc_n rows, pitch 20
    __shared__ float wap_s[128*20];    // Wap rows, pitch 20

    const int t  = threadIdx.x;
    const int j  = t>>3;        // 0..127 output column
    const int kc = t&7;         // 0..7 k-chunk
    const int row0 = blockIdx.x*16;

    // --- persistent weights: 48 + 4 floats ---
    const float4* whh4 = (const float4*)whh;
    float4 whr[4], whz[4], whn[4];
    #pragma unroll
    for (int i=0;i<4;i++){
        whr[i] = whh4[(      j)*32 + kc*4 + i];
        whz[i] = whh4[(128 + j)*32 + kc*4 + i];
        whn[i] = whh4[(256 + j)*32 + kc*4 + i];
    }
    const float wro0 = ws[WS_WC + j*16 + 2*kc];
    const float wro1 = ws[WS_WC + j*16 + 2*kc+1];
    const float wzo0 = ws[WS_WC + (128+j)*16 + 2*kc];
    const float wzo1 = ws[WS_WC + (128+j)*16 + 2*kc+1];
    const float bcrt = ws[WS_BC+j]     + bhh[j];
    const float bczt = ws[WS_BC+128+j] + bhh[128+j];
    const float bcn  = ws[WS_BC+256+j];
    const float bhn  = bhh[256+j];
    const float baj  = ba[j];
    const int hoff_j = (j>>4)*20 + (j&15);

    // --- stage Wc_n / Wap into LDS ---
    {
        int f = t&15, jr = t>>4;   // jr 0..63
        wn_s [jr*20+f]      = ws[WS_WC + (256+jr)*16 + f];
        wn_s [(jr+64)*20+f] = ws[WS_WC + (256+jr+64)*16 + f];
        wap_s[jr*20+f]      = ws[WS_WAP + jr*16 + f];
        wap_s[(jr+64)*20+f] = ws[WS_WAP + (jr+64)*16 + f];
    }
    // --- stage h0 + obs(0) ---
    if (t < 512){
        int rr = t>>5, c0 = (t&31)*4;
        float4 hv = *(const float4*)&h0[(size_t)(row0+rr)*128 + c0];
        *(float4*)&h_s[0][rr*164 + (c0>>4)*20 + (c0&15)] = hv;
    }
    if (t < 256){
        int rr = t>>4, c = t&15;
        obs_s[rr*20+c] = (c<15) ? obs[((size_t)(row0+rr)*64 + 0)*15 + c] : 0.f;
    }
    __syncthreads();

    for (int s=0;s<64;s++){
        const float* hcur = h_s[s&1];
        float*       hnxt = h_s[(s+1)&1];

        // prefetch obs(s+1) into a register: vmem latency overlaps the dot phase
        float obs_pf = 0.f;
        if (t < 256){
            int rr = t>>4, c = t&15;
            int sn = (s<63) ? s+1 : s;
            obs_pf = (c<15) ? obs[((size_t)(row0+rr)*64 + sn)*15 + c] : 0.f;
        }

        float sAr=0.f,sAz=0.f,sAn=0.f, sBr=0.f,sBz=0.f,sBn=0.f;
        #pragma unroll
        for (int p=0;p<8;p++){
            const int r0=2*p, r1=2*p+1;
            float pr0=0.f,pz0=0.f,pn0=0.f, pr1=0.f,pz1=0.f,pn1=0.f;
            {
                const float* hb = &hcur[r0*164 + kc*20];
                #pragma unroll
                for (int i=0;i<4;i++){
                    float4 hv = *(const float4*)&hb[i*4];
                    acc4(pr0,hv,whr[i]); acc4(pz0,hv,whz[i]); acc4(pn0,hv,whn[i]);
                }
                float o0 = obs_s[r0*20+2*kc], o1 = obs_s[r0*20+2*kc+1];
                pr0 = fmaf(o0,wro0, fmaf(o1,wro1, pr0));
                pz0 = fmaf(o0,wzo0, fmaf(o1,wzo1, pz0));
            }
            {
                const float* hb = &hcur[r1*164 + kc*20];
                #pragma unroll
                for (int i=0;i<4;i++){
                    float4 hv = *(const float4*)&hb[i*4];
                    acc4(pr1,hv,whr[i]); acc4(pz1,hv,whz[i]); acc4(pn1,hv,whn[i]);
                }
                float o0 = obs_s[r1*20+2*kc], o1 = obs_s[r1*20+2*kc+1];
                pr1 = fmaf(o0,wro0, fmaf(o1,wro1, pr1));
                pz1 = fmaf(o0,wzo0, fmaf(o1,wzo1, pz1));
            }
            // reduce over kc octet (lanes differ in bits 0..2)
            pr0 += __shfl_xor(pr0,1); pr0 += __shfl_xor(pr0,2); pr0 += __shfl_xor(pr0,4);
            pz0 += __shfl_xor(pz0,1); pz0 += __shfl_xor(pz0,2); pz0 += __shfl_xor(pz0,4);
            pn0 += __shfl_xor(pn0,1); pn0 += __shfl_xor(pn0,2); pn0 += __shfl_xor(pn0,4);
            pr1 += __shfl_xor(pr1,1); pr1 += __shfl_xor(pr1,2); pr1 += __shfl_xor(pr1,4);
            pz1 += __shfl_xor(pz1,1); pz1 += __shfl_xor(pz1,2); pz1 += __shfl_xor(pz1,4);
            pn1 += __shfl_xor(pn1,1); pn1 += __shfl_xor(pn1,2); pn1 += __shfl_xor(pn1,4);
            // latch: lane kc keeps rows {kc, kc+8}
            if ((r0&7)==kc){ if (r0<8){sAr=pr0;sAz=pz0;sAn=pn0;} else {sBr=pr0;sBz=pz0;sBn=pn0;} }
            if ((r1&7)==kc){ if (r1<8){sAr=pr1;sAz=pz1;sAn=pn1;} else {sBr=pr1;sBz=pz1;sBn=pn1;} }
        }

        // ---- finalize rows kc and kc+8 (all lanes in parallel) ----
        #pragma unroll
        for (int u=0;u<2;u++){
            const int r = kc + 8*u;
            float sr = u ? sBr : sAr;
            float sz = u ? sBz : sAz;
            float sn = u ? sBn : sAn;
            const float* ob = &obs_s[r*20];
            float4 o0 = *(const float4*)&ob[0],  o1 = *(const float4*)&ob[4];
            float4 o2 = *(const float4*)&ob[8],  o3 = *(const float4*)&ob[12];
            float gin = bcn;
            acc4(gin,o0,*(const float4*)&wn_s[j*20+ 0]);
            acc4(gin,o1,*(const float4*)&wn_s[j*20+ 4]);
            acc4(gin,o2,*(const float4*)&wn_s[j*20+ 8]);
            acc4(gin,o3,*(const float4*)&wn_s[j*20+12]);
            float ae = baj;
            acc4(ae,o0,*(const float4*)&wap_s[j*20+ 0]);
            acc4(ae,o1,*(const float4*)&wap_s[j*20+ 4]);
            acc4(ae,o2,*(const float4*)&wap_s[j*20+ 8]);
            acc4(ae,o3,*(const float4*)&wap_s[j*20+12]);
            float rg = 1.f/(1.f+__expf(-(sr+bcrt)));
            float zg = 1.f/(1.f+__expf(-(sz+bczt)));
            float nx = fmaf(rg, sn + bhn, gin);
            float e2 = __expf(2.f*nx);
            float ng = 1.f - 2.f/(e2+1.f);          // tanh(nx)
            float hold = hcur[r*164 + hoff_j];
            float hn = fmaf(zg, hold-ng, ng);       // (1-z)n + z*h
            hnxt[r*164 + hoff_j] = hn;
            air_s[r*132 + j] = hn + ae;
            if (s==63) out[(size_t)N_ + (size_t)(row0+r)*128 + j] = hn;
        }
        __syncthreads();   // bar_1: hcur/obs reads done; hnxt/air_s written

        // ---- coalesced air write + commit prefetched obs(s+1) ----
        if (t < 512){
            int rr = t>>5, c0 = (t&31)*4;
            float4 av = *(const float4*)&air_s[rr*132 + c0];
            *(float4*)&air[((size_t)(row0+rr)*64 + s)*128 + c0] = av;
        }
        if (t < 256){
            int rr = t>>4, c = t&15;
            obs_s[rr*20+c] = obs_pf;
        }
        __syncthreads();   // bar_2
    }
}

// ---------------- Kernel B1: attention (per-token), in-place combined ----------------
__global__ __launch_bounds__(512,2) void attn_kernel(
    const float* __restrict__ obs, const float* __restrict__ wo,
    const float* __restrict__ bo,  const float* __restrict__ ws,
    float* __restrict__ air)
{
    __shared__ float X_s[16*AP];
    __shared__ float ctx_s[16*AP];
    __shared__ float comb_s[16*AP];
    __shared__ float obs_m[16][8];
    __shared__ float part[16][2][8];
    __shared__ float attn_s[16][4][2];
    __shared__ float mu_s[16], rs_s[16];
    __shared__ float kmu_s[16][2], krs_s[16][2];
    __shared__ int   kmask_s[16][2];
    __shared__ int   bothm_s[16];

    const int t = threadIdx.x;
    const int j = t>>2, kc = t&3;
    const int w = t>>6;
    const int n0 = blockIdx.x*16;
    const int jaddr_off = (j>>5)*40 + (j&31);

    // weights in registers
    const float4* wqp4 = (const float4*)(ws + WS_WQP);
    const float4* wo4g = (const float4*)wo;
    float4 wq4[8], woo4[8];
    #pragma unroll
    for (int i=0;i<8;i++){ wq4[i] = wqp4[j*32 + kc*8 + i]; woo4[i] = wo4g[j*32 + kc*8 + i]; }
    const float sqj = ws[WS_SQ+j], eqj = ws[WS_EQ+j];
    const float4 kcj = ((const float4*)(ws+WS_KC))[j];
    const float ek1j = ws[WS_EK1+j], skj = ws[WS_SK+j], ek2j = ws[WS_EK2+j];
    const float4 vcj = ((const float4*)(ws+WS_VC))[j];
    const float vbj = ws[WS_VB+j];
    const float boj = bo[j];

    // stage X tile + LN stats + missile staging/stats
    {
        int rr = t>>5, c0 = (t&31)*4;
        float4 xv = *(const float4*)&air[(size_t)(n0+rr)*128 + c0];
        *(float4*)&X_s[caddr(rr,c0)] = xv;
        float sm = xv.x+xv.y+xv.z+xv.w;
        float s2 = fmaf(xv.x,xv.x, fmaf(xv.y,xv.y, fmaf(xv.z,xv.z, xv.w*xv.w)));
        #pragma unroll
        for (int m=1;m<32;m<<=1){ sm += __shfl_xor(sm,m); s2 += __shfl_xor(s2,m); }
        if ((t&31)==0){
            float mu = sm*(1.f/128.f);
            float var = s2*(1.f/128.f) - mu*mu;
            mu_s[rr]=mu; rs_s[rr]=rsqrtf(var+1e-5f);
        }
    }
    if (t>=128 && t<256){
        int idx = t-128; int rr = idx>>3, f = idx&7;
        obs_m[rr][f] = obs[(size_t)(n0+rr)*15 + f];
    }
    if (t<32){
        int rr = t&15, mi = t>>4;
        const float* mp = &obs[(size_t)(n0+rr)*15 + mi*4];
        float m0=mp[0], m1=mp[1], m2=mp[2], m3=mp[3];
        const float tol1 = 1e-8f + 1e-5f, tol0 = 1e-8f;
        kmask_s[rr][mi] = (fabsf(m0-1.f)<=tol1)&&(fabsf(m1)<=tol0)&&
                          (fabsf(m2-1.f)<=tol1)&&(fabsf(m3)<=tol0);
        float mv[4]={m0,m1,m2,m3};
        float mu = ws[WS_MBC];
        #pragma unroll
        for (int f=0;f<4;f++) mu = fmaf(ws[WS_MV+f], mv[f], mu);
        float e2 = ws[WS_C0];
        #pragma unroll
        for (int a4=0;a4<4;a4++){
            e2 = fmaf(ws[WS_QLIN+a4], mv[a4], e2);
            #pragma unroll
            for (int b4=0;b4<4;b4++) e2 = fmaf(ws[WS_QQ+a4*4+b4]*mv[a4], mv[b4], e2);
        }
        float var = e2 - mu*mu;
        kmu_s[rr][mi]=mu; krs_s[rr][mi]=rsqrtf(var+1e-5f);
    }
    __syncthreads();

    // q matvec: full dots via kc-butterfly; owner keeps rows 4kc..4kc+3
    float qown[4];
    #pragma unroll
    for (int r=0;r<16;r++){
        float acc = 0.f;
        const float* xb = &X_s[r*AP + kc*40];
        #pragma unroll
        for (int i=0;i<8;i++) acc4(acc, *(const float4*)&xb[i*4], wq4[i]);
        acc += __shfl_xor(acc,1); acc += __shfl_xor(acc,2);
        if (kc == (r>>2)) qown[r&3] = acc;
    }
    // scores: q*k products, reduce over 16 j within wave, stash per-wave partials
    #pragma unroll
    for (int oi=0;oi<4;oi++){
        int r = kc*4 + oi;
        float qv = fmaf(rs_s[r], qown[oi] - mu_s[r]*sqj, eqj);
        float4 m0v = *(const float4*)&obs_m[r][0];
        float4 m1v = *(const float4*)&obs_m[r][4];
        float k0 = fmaf(krs_s[r][0], dot4(kcj,m0v)+ek1j - kmu_s[r][0]*skj, ek2j);
        float k1 = fmaf(krs_s[r][1], dot4(kcj,m1v)+ek1j - kmu_s[r][1]*skj, ek2j);
        float p0 = qv*k0, p1 = qv*k1;
        #pragma unroll
        for (int m=4;m<64;m<<=1){ p0 += __shfl_xor(p0,m); p1 += __shfl_xor(p1,m); }
        if ((t&63)==kc){ part[r][0][w]=p0; part[r][1][w]=p1; }
    }
    __syncthreads();
    if (t<64){
        int rr = t&15, hd = t>>4;
        float s0 = part[rr][0][2*hd] + part[rr][0][2*hd+1];
        float s1 = part[rr][1][2*hd] + part[rr][1][2*hd+1];
        const float scale = 0.17677669529663687f;  // 1/sqrt(32)
        s0 *= scale; s1 *= scale;
        int m0 = kmask_s[rr][0], m1 = kmask_s[rr][1];
        float a0, a1;
        if (m0 && m1) { a0=0.f; a1=0.f; if (hd==0) bothm_s[rr]=1; }
        else {
            if (hd==0) bothm_s[rr]=0;
            if (m0)      { a0=0.f; a1=1.f; }
            else if (m1) { a0=1.f; a1=0.f; }
            else {
                float mx = fmaxf(s0,s1);
                float e0 = __expf(s0-mx), e1 = __expf(s1-mx);
                float inv = 1.f/(e0+e1);
                a0 = e0*inv; a1 = e1*inv;
            }
        }
        attn_s[rr][hd][0]=a0; attn_s[rr][hd][1]=a1;
    }
    __syncthreads();
    // ctx
    {
        int hd = j>>5;
        #pragma unroll
        for (int oi=0;oi<4;oi++){
            int r = kc*4 + oi;
            float4 m0v = *(const float4*)&obs_m[r][0];
            float4 m1v = *(const float4*)&obs_m[r][4];
            float v0 = dot4(vcj,m0v)+vbj, v1 = dot4(vcj,m1v)+vbj;
            ctx_s[r*AP + jaddr_off] = attn_s[r][hd][0]*v0 + attn_s[r][hd][1]*v1;
        }
    }
    __syncthreads();
    // attn_out matvec + nan guard + residual
    float aown[4];
    #pragma unroll
    for (int r=0;r<16;r++){
        float acc = 0.f;
        const float* zb = &ctx_s[r*AP + kc*40];
        #pragma unroll
        for (int i=0;i<8;i++) acc4(acc, *(const float4*)&zb[i*4], woo4[i]);
        acc += __shfl_xor(acc,1); acc += __shfl_xor(acc,2);
        if (kc == (r>>2)) aown[r&3] = acc;
    }
    #pragma unroll
    for (int oi=0;oi<4;oi++){
        int r = kc*4 + oi;
        float ao = bothm_s[r] ? 0.f : (aown[oi] + boj);
        comb_s[r*AP + jaddr_off] = X_s[r*AP + jaddr_off] + ao;
    }
    __syncthreads();
    // write combined back in place over air
    {
        int rr = t>>5, c0 = (t&31)*4;
        float4 cv = *(const float4*)&comb_s[caddr(rr,c0)];
        *(float4*)&air[(size_t)(n0+rr)*128 + c0] = cv;
    }
}

// ---------------- Kernel B2: MLP head ----------------
__global__ __launch_bounds__(512,2) void mlp_kernel(
    const float* __restrict__ comb,
    const float* __restrict__ w0, const float* __restrict__ b0,
    const float* __restrict__ w1, const float* __restrict__ b1,
    const float* __restrict__ fcw, const float* __restrict__ fcb,
    float* __restrict__ out)
{
    __shared__ float C_s[16*AP];
    __shared__ float H_s[16*AP];
    __shared__ float part2[16][8];

    const int t = threadIdx.x;
    const int j = t>>2, kc = t&3;
    const int w = t>>6;
    const int n0 = blockIdx.x*16;
    const int jaddr_off = (j>>5)*40 + (j&31);

    const float4* w04g = (const float4*)w0;
    const float4* w14g = (const float4*)w1;
    float4 w04[8], w14[8];
    #pragma unroll
    for (int i=0;i<8;i++){ w04[i] = w04g[j*32 + kc*8 + i]; w14[i] = w14g[j*32 + kc*8 + i]; }
    const float b0j = b0[j], b1j = b1[j], fcj = fcw[j];

    {
        int rr = t>>5, c0 = (t&31)*4;
        float4 cv = *(const float4*)&comb[(size_t)(n0+rr)*128 + c0];
        *(float4*)&C_s[caddr(rr,c0)] = cv;
    }
    __syncthreads();
    // mlp0
    float hown[4];
    #pragma unroll
    for (int r=0;r<16;r++){
        float acc = 0.f;
        const float* cb = &C_s[r*AP + kc*40];
        #pragma unroll
        for (int i=0;i<8;i++) acc4(acc, *(const float4*)&cb[i*4], w04[i]);
        acc += __shfl_xor(acc,1); acc += __shfl_xor(acc,2);
        if (kc == (r>>2)){
            float v = acc + b0j;
            hown[r&3] = (v > 0.f) ? v : 0.01f*v;
        }
    }
    #pragma unroll
    for (int oi=0;oi<4;oi++) H_s[(kc*4+oi)*AP + jaddr_off] = hown[oi];
    __syncthreads();
    // mlp1 + fco
    float pown[4];
    #pragma unroll
    for (int r=0;r<16;r++){
        float acc = 0.f;
        const float* hb = &H_s[r*AP + kc*40];
        #pragma unroll
        for (int i=0;i<8;i++) acc4(acc, *(const float4*)&hb[i*4], w14[i]);
        acc += __shfl_xor(acc,1); acc += __shfl_xor(acc,2);
        if (kc == (r>>2)){
            float v = acc + b1j;
            v = (v > 0.f) ? v : 0.01f*v;
            pown[r&3] = v * fcj;
        }
    }
    #pragma unroll
    for (int oi=0;oi<4;oi++){
        float p = pown[oi];
        #pragma unroll
        for (int m=4;m<64;m<<=1) p += __shfl_xor(p,m);
        if ((t&63)==kc) part2[kc*4+oi][w] = p;
    }
    __syncthreads();
    if (t<16){
        float a = 0.f;
        #pragma unroll
        for (int k=0;k<8;k++) a += part2[t][k];
        out[n0 + t] = a + fcb[0];
    }
}

extern "C" void kernel_launch(void* const* d_in, const int* in_sizes, int n_in,
                              void* d_out, int out_size, void* d_ws, size_t ws_size,
                              hipStream_t stream) {
    const float* obs       = (const float*)d_in[0];
    const float* h0        = (const float*)d_in[1];
    const float* enc_air_w = (const float*)d_in[2];
    const float* enc_air_b = (const float*)d_in[3];
    const float* enc_m_w   = (const float*)d_in[4];
    const float* enc_m_b   = (const float*)d_in[5];
    const float* gru_wih   = (const float*)d_in[6];
    const float* gru_whh   = (const float*)d_in[7];
    const float* gru_bih   = (const float*)d_in[8];
    const float* gru_bhh   = (const float*)d_in[9];
    const float* qln_w     = (const float*)d_in[10];
    const float* qln_b     = (const float*)d_in[11];
    const float* kln_w     = (const float*)d_in[12];
    const float* kln_b     = (const float*)d_in[13];
    const float* attn_in_w = (const float*)d_in[14];
    const float* attn_in_b = (const float*)d_in[15];
    const float* attn_out_w= (const float*)d_in[16];
    const float* attn_out_b= (const float*)d_in[17];
    const float* mlp0_w    = (const float*)d_in[18];
    const float* mlp0_b    = (const float*)d_in[19];
    const float* mlp1_w    = (const float*)d_in[20];
    const float* mlp1_b    = (const float*)d_in[21];
    const float* fco_w     = (const float*)d_in[22];
    const float* fco_b     = (const float*)d_in[23];
    float* out = (float*)d_out;
    float* ws  = (float*)d_ws;
    float* air = ws + WS_AIR;

    precompute_kernel<<<dim3(105), dim3(256), 0, stream>>>(
        enc_air_w, enc_air_b, enc_m_w, enc_m_b, gru_wih, gru_bih,
        qln_w, qln_b, kln_w, kln_b, attn_in_w, attn_in_b, ws);

    gru_kernel<<<dim3(256), dim3(1024), 0, stream>>>(
        obs, h0, gru_whh, gru_bhh, enc_air_b, ws, air, out);

    attn_kernel<<<dim3(N_/16), dim3(512), 0, stream>>>(
        obs, attn_out_w, attn_out_b, ws, air);

    mlp_kernel<<<dim3(N_/16), dim3(512), 0, stream>>>(
        air, mlp0_w, mlp0_b, mlp1_w, mlp1_b, fco_w, fco_b, out);
}